// Round 16
// baseline (228.494 us; speedup 1.0000x reference)
//
#include <hip/hip_runtime.h>
#include <hip/hip_bf16.h>

#define NB 16
#define VV 5000
#define NFD 352
#define KD 120
#define NCH 5
#define SLABSZ (352 * 120)

typedef __attribute__((ext_vector_type(8))) short short8;
typedef __attribute__((ext_vector_type(4))) float float4v;

__device__ __forceinline__ unsigned short bfb(float a) {
    return __builtin_bit_cast(unsigned short, __float2bfloat16(a));
}

// split fp32 -> bf16 hi + bf16 lo(residual), pack 8 of each into int4
__device__ __forceinline__ void pack8(const float* f, int4& hi, int4& lo) {
    unsigned short h[8], l[8];
    #pragma unroll
    for (int j = 0; j < 8; ++j) {
        const float a = f[j];
        const __hip_bfloat16 hb = __float2bfloat16(a);
        h[j] = __builtin_bit_cast(unsigned short, hb);
        l[j] = bfb(a - __bfloat162float(hb));
    }
    hi.x = h[0] | (h[1] << 16); hi.y = h[2] | (h[3] << 16);
    hi.z = h[4] | (h[5] << 16); hi.w = h[6] | (h[7] << 16);
    lo.x = l[0] | (l[1] << 16); lo.y = l[2] | (l[3] << 16);
    lo.z = l[4] | (l[5] << 16); lo.w = l[6] | (l[7] << 16);
}

// ---------------------------------------------------------------------------
// proj v3 (round-8/15 state, UNCHANGED — empirical best: ~119us):
// BK=32, double-buffered LDS ping-pong (2 x 32KB), 2-deep register prefetch
// (P/Q named sets), ONE barrier per step: loads(st+2) || compute(st) ||
// pack+write(st+1 -> other buf). Tile 128x128, 4 waves 2x2.
// v4(no-LDS)/v5(fp32-LDS)/v6b(80B-pad)/v7(2nd staging set)/v8(128m 3-blk)
// all measured WORSE (spill or LDS-issue or latency) — plateau established.
// ---------------------------------------------------------------------------
__global__ __launch_bounds__(256, 2) void proj_mfma(
    const float* __restrict__ fx, const float* __restrict__ fy,
    const float* __restrict__ ex, const float* __restrict__ ey,
    float* __restrict__ partials)
{
    const int t = threadIdx.x;

    // ---- bijective XCD-chunk swizzle: 480 blocks = 8 XCDs x 60 ----
    int lin = blockIdx.x + 15 * (blockIdx.y + 2 * blockIdx.z);
    lin = (lin & 7) * 60 + (lin >> 3);
    const int xx   = lin % 15;
    const int rest = lin / 15;
    const int wh = rest & 1;
    const int b  = rest >> 1;
    const int mt = xx % 3;
    const int ch = xx / 3;

    const float* Ab = (wh ? fy : fx) + (size_t)b * VV * NFD;
    const float* Bb = (wh ? ey : ex) + (size_t)b * VV * KD;
    const int m0 = mt * 128;

    __shared__ int4 smem4[4096];                 // 64 KB = 2 x 32KB buffers
    unsigned char* smem = (unsigned char*)smem4;

    // ---- staging precompute: 2 A units + 2 B units (m, k-octet) ----
    int acol[2], awb[2], ao[2];
    #pragma unroll
    for (int i = 0; i < 2; ++i) {
        const int q = i * 256 + t;               // 0..511
        const int m = q & 127;
        const int o = q >> 7;                    // k-octet 0..3
        acol[i] = min(m0 + m, NFD - 1);          // clamp: dup cols never stored to C
        awb[i]  = m * 64 + ((o ^ ((m >> 1) & 3)) * 16);
        ao[i]   = o;
    }
    int bcol[2], bwb[2], bo[2];
    #pragma unroll
    for (int i = 0; i < 2; ++i) {
        const int q = i * 256 + t;
        const int n = q & 127;
        const int o = q >> 7;
        bcol[i] = min(n, KD - 1);
        bwb[i]  = n * 64 + ((o ^ ((n >> 1) & 3)) * 16);
        bo[i]   = o;
    }

    // ---- wave geometry: 4 waves as 2x2, wave tile 64x64 ----
    const int lane = t & 63;
    const int wid  = t >> 6;
    const int wm = wid >> 1, wn = wid & 1;
    const int r16 = lane & 15;
    const int g   = lane >> 4;

    int abase[4], bbase[4];
    #pragma unroll
    for (int mf = 0; mf < 4; ++mf) {
        const int m = wm * 64 + mf * 16 + r16;
        abase[mf] = m * 64 + ((g ^ ((m >> 1) & 3)) * 16);
    }
    #pragma unroll
    for (int nf = 0; nf < 4; ++nf) {
        const int n = wn * 64 + nf * 16 + r16;
        bbase[nf] = n * 64 + ((g ^ ((n >> 1) & 3)) * 16);
    }

    float4v acc[4][4];
    #pragma unroll
    for (int mf = 0; mf < 4; ++mf)
        #pragma unroll
        for (int nf = 0; nf < 4; ++nf)
            acc[mf][nf] = float4v{0.f, 0.f, 0.f, 0.f};

    const int step0 = ch * 32;                   // V-steps of 32
    const int nst   = (ch < 4) ? 32 : 30;        // 4*32+30 = 158 steps >= 5000/32

    float faP[2][8], fbP[2][8], faQ[2][8], fbQ[2][8];

    auto do_loads = [&](int st, float (&fa)[2][8], float (&fb)[2][8]) {
        const int v0 = (step0 + st) * 32;
        if (v0 + 32 <= VV) {
            #pragma unroll
            for (int i = 0; i < 2; ++i) {
                const float* pa = Ab + (size_t)(v0 + ao[i] * 8) * NFD + acol[i];
                #pragma unroll
                for (int j = 0; j < 8; ++j) fa[i][j] = pa[j * NFD];
            }
            #pragma unroll
            for (int i = 0; i < 2; ++i) {
                const float* pb = Bb + (size_t)(v0 + bo[i] * 8) * KD + bcol[i];
                #pragma unroll
                for (int j = 0; j < 8; ++j) fb[i][j] = pb[j * KD];
            }
        } else {
            #pragma unroll
            for (int i = 0; i < 2; ++i) {
                const float* pa = Ab + (size_t)(v0 + ao[i] * 8) * NFD + acol[i];
                #pragma unroll
                for (int j = 0; j < 8; ++j) {
                    const int v = v0 + ao[i] * 8 + j;
                    fa[i][j] = (v < VV) ? pa[j * NFD] : 0.f;
                }
            }
            #pragma unroll
            for (int i = 0; i < 2; ++i) {
                const float* pb = Bb + (size_t)(v0 + bo[i] * 8) * KD + bcol[i];
                #pragma unroll
                for (int j = 0; j < 8; ++j) {
                    const int v = v0 + bo[i] * 8 + j;
                    fb[i][j] = (v < VV) ? pb[j * KD] : 0.f;
                }
            }
        }
    };

    auto do_writes = [&](int bufb, float (&fa)[2][8], float (&fb)[2][8]) {
        #pragma unroll
        for (int i = 0; i < 2; ++i) {
            int4 hi, lo;
            pack8(fa[i], hi, lo);
            *(int4*)(smem + bufb + awb[i])        = hi;
            *(int4*)(smem + bufb + awb[i] + 8192) = lo;
        }
        #pragma unroll
        for (int i = 0; i < 2; ++i) {
            int4 hi, lo;
            pack8(fb[i], hi, lo);
            *(int4*)(smem + bufb + 16384 + bwb[i]) = hi;
            *(int4*)(smem + bufb + 24576 + bwb[i]) = lo;
        }
    };

    auto compute = [&](int bufb) {
        short8 ah[4], al[4], bh[4], bl[4];
        #pragma unroll
        for (int mf = 0; mf < 4; ++mf) {
            ah[mf] = *(const short8*)(smem + bufb + abase[mf]);
            al[mf] = *(const short8*)(smem + bufb + abase[mf] + 8192);
        }
        #pragma unroll
        for (int nf = 0; nf < 4; ++nf) {
            bh[nf] = *(const short8*)(smem + bufb + 16384 + bbase[nf]);
            bl[nf] = *(const short8*)(smem + bufb + 24576 + bbase[nf]);
        }
        #pragma unroll
        for (int mf = 0; mf < 4; ++mf)
            #pragma unroll
            for (int nf = 0; nf < 4; ++nf) {
                acc[mf][nf] = __builtin_amdgcn_mfma_f32_16x16x32_bf16(ah[mf], bh[nf], acc[mf][nf], 0, 0, 0);
                acc[mf][nf] = __builtin_amdgcn_mfma_f32_16x16x32_bf16(ah[mf], bl[nf], acc[mf][nf], 0, 0, 0);
                acc[mf][nf] = __builtin_amdgcn_mfma_f32_16x16x32_bf16(al[mf], bh[nf], acc[mf][nf], 0, 0, 0);
            }
    };

    // ---- prologue: prefetch steps 0,1; publish step 0 into buf0 ----
    do_loads(0, faP, fbP);
    do_loads(1, faQ, fbQ);
    do_writes(0, faP, fbP);
    __syncthreads();

    // ---- main loop: 2 steps per iteration, 1 barrier per step ----
    for (int i = 0; i < nst / 2; ++i) {
        const int st = 2 * i;
        if (st + 2 < nst) do_loads(st + 2, faP, fbP);
        compute(0);
        do_writes(32768, faQ, fbQ);          // st+1 (always < nst: nst even)
        __syncthreads();
        if (st + 3 < nst) do_loads(st + 3, faQ, fbQ);
        compute(32768);
        if (st + 2 < nst) do_writes(0, faP, fbP);
        __syncthreads();
    }

    // ---- store partial C tile: slab[m*120 + n] ----
    float* slab = partials + (size_t)((ch * 2 + wh) * NB + b) * SLABSZ;
    #pragma unroll
    for (int mf = 0; mf < 4; ++mf) {
        const int mrow = mt * 128 + wm * 64 + mf * 16 + g * 4;
        #pragma unroll
        for (int nf = 0; nf < 4; ++nf) {
            const int n = wn * 64 + nf * 16 + r16;
            if (n < KD) {
                #pragma unroll
                for (int r = 0; r < 4; ++r) {
                    const int m = mrow + r;
                    if (m < NFD) slab[(size_t)m * KD + n] = acc[mf][nf][r];
                }
            }
        }
    }
}

// ---------------------------------------------------------------------------
// gram_fused: reduce_k folded into gram. Reads the 5 partial chunks directly
// (sum at staging) — eliminates the reduce kernel + fhat/ghat buffers.
// C[b][which] 120x120 = A^T B over V=352, A/B = summed partial slabs.
// Extra cost: staging reads 5x (35 -> 173 MB, L2-resident, ~+4us aggregate);
// saves reduce's dispatch (~10-12us) + one launch gap.
// partials slab layout [f][k] row-major == old fhat layout, so indexing is
// identical to the old gemm_tn_64x64 with A/B -> chunk-summed loads.
// ---------------------------------------------------------------------------
__global__ __launch_bounds__(256) void gram_fused(
    const float* __restrict__ partials,
    float* __restrict__ ftf, float* __restrict__ gtg, float* __restrict__ ftg)
{
    const int b = blockIdx.z;
    const int which = blockIdx.y;
    const int m0 = (blockIdx.x & 1) * 64;
    const int n0 = (blockIdx.x >> 1) * 64;

    const int whA = (which == 1) ? 1 : 0;     // 0:F 1:G 2:F
    const int whB = (which == 0) ? 0 : 1;     // 0:F 1:G 2:G
    const float* A = partials + (size_t)(whA * NB + b) * SLABSZ;
    const float* B = partials + (size_t)(whB * NB + b) * SLABSZ;
    const size_t chs = (size_t)2 * NB * SLABSZ;   // chunk stride
    float* C = ((which == 0) ? ftf : (which == 1) ? gtg : ftg) + (size_t)b * KD * KD;

    const int M = KD, N = KD, V = NFD;

    __shared__ float As[16][64];
    __shared__ float Bs[16][64];

    const int tid = threadIdx.x;
    const int tx = tid & 15;
    const int ty = tid >> 4;
    const int sr = tid >> 4;
    const int sc = (tid & 15) << 2;

    float acc[4][4] = {{0.f,0.f,0.f,0.f},{0.f,0.f,0.f,0.f},
                       {0.f,0.f,0.f,0.f},{0.f,0.f,0.f,0.f}};

    for (int v0 = 0; v0 < V; v0 += 16) {      // V=352, 16 | 352 -> no v guard
        const int v = v0 + sr;
        float4 av; av.x = av.y = av.z = av.w = 0.f;
        float4 bv; bv.x = bv.y = bv.z = bv.w = 0.f;
        {
            const int ca = m0 + sc;
            const float* Ar = A + (size_t)v * KD;
            if (ca + 3 < M) {
                #pragma unroll
                for (int c = 0; c < NCH; ++c) {
                    const float4 t4 = *(const float4*)(Ar + c * chs + ca);
                    av.x += t4.x; av.y += t4.y; av.z += t4.z; av.w += t4.w;
                }
            } else {
                #pragma unroll
                for (int c = 0; c < NCH; ++c) {
                    const float* p = Ar + c * chs;
                    if (ca + 0 < M) av.x += p[ca + 0];
                    if (ca + 1 < M) av.y += p[ca + 1];
                    if (ca + 2 < M) av.z += p[ca + 2];
                    if (ca + 3 < M) av.w += p[ca + 3];
                }
            }
            const int cb = n0 + sc;
            const float* Br = B + (size_t)v * KD;
            if (cb + 3 < N) {
                #pragma unroll
                for (int c = 0; c < NCH; ++c) {
                    const float4 t4 = *(const float4*)(Br + c * chs + cb);
                    bv.x += t4.x; bv.y += t4.y; bv.z += t4.z; bv.w += t4.w;
                }
            } else {
                #pragma unroll
                for (int c = 0; c < NCH; ++c) {
                    const float* p = Br + c * chs;
                    if (cb + 0 < N) bv.x += p[cb + 0];
                    if (cb + 1 < N) bv.y += p[cb + 1];
                    if (cb + 2 < N) bv.z += p[cb + 2];
                    if (cb + 3 < N) bv.w += p[cb + 3];
                }
            }
        }
        __syncthreads();
        *(float4*)&As[sr][sc] = av;
        *(float4*)&Bs[sr][sc] = bv;
        __syncthreads();

        #pragma unroll
        for (int kk = 0; kk < 16; ++kk) {
            const float4 a4 = *(const float4*)&As[kk][ty << 2];
            const float4 b4 = *(const float4*)&Bs[kk][tx << 2];
            const float a[4]  = {a4.x, a4.y, a4.z, a4.w};
            const float bb[4] = {b4.x, b4.y, b4.z, b4.w};
            #pragma unroll
            for (int i = 0; i < 4; ++i)
                #pragma unroll
                for (int j = 0; j < 4; ++j)
                    acc[i][j] = fmaf(a[i], bb[j], acc[i][j]);
        }
    }

    #pragma unroll
    for (int i = 0; i < 4; ++i) {
        const int m = m0 + (ty << 2) + i;
        if (m < M) {
            #pragma unroll
            for (int j = 0; j < 4; ++j) {
                const int n = n0 + (tx << 2) + j;
                if (n < N) C[(size_t)m * N + n] = acc[i][j];
            }
        }
    }
}

// ---------------------------------------------------------------------------
// solve v6 (unchanged, passing): 480-thread Gauss-Jordan, 60 named scalars,
// padded 20-float prow segments (bank-clean), R=4 row reuse.
// ---------------------------------------------------------------------------
__device__ __forceinline__ float ldval(const float* __restrict__ A, const float* __restrict__ B,
                                       int pair, int row, int col) {
    if (col < KD) return A[row * KD + col];
    const int l = col - KD;
    return pair ? B[l * KD + row] : B[row * KD + l];
}

#define FOR15(OP) OP(0) OP(1) OP(2) OP(3) OP(4) OP(5) OP(6) OP(7) OP(8) OP(9) \
                  OP(10) OP(11) OP(12) OP(13) OP(14)

__global__ __launch_bounds__(480, 1) void solve_kernel(
    const float* __restrict__ ftf, const float* __restrict__ gtg,
    const float* __restrict__ ftg, float* __restrict__ out)
{
    const int pair = blockIdx.x;
    const int b = blockIdx.y;
    const int tid = threadIdx.x;
    const int cg = tid & 15;
    const int rg = tid >> 4;
    const int cbase = cg * 15;
    const int r0 = rg * 4;
    const int seg = cg * 20;

    const float* Ag = ((pair == 0) ? ftf : gtg) + (size_t)b * KD * KD;
    const float* Bg = ftg + (size_t)b * KD * KD;

    __shared__ __align__(16) float prow[2][320];
    __shared__ __align__(16) float pcol[2][120];

    #define DECL(I) float w##I = ldval(Ag, Bg, pair, r0 + 0, cbase + (I)); \
                    float x##I = ldval(Ag, Bg, pair, r0 + 1, cbase + (I)); \
                    float y##I = ldval(Ag, Bg, pair, r0 + 2, cbase + (I)); \
                    float z##I = ldval(Ag, Bg, pair, r0 + 3, cbase + (I));
    FOR15(DECL)
    #undef DECL

    if (rg == 0) {
        #define PUB0(I) prow[0][seg + (I)] = w##I;
        FOR15(PUB0)
        #undef PUB0
    }
    if (cg == 0) *(float4*)&pcol[0][r0] = float4{w0, x0, y0, z0};
    __syncthreads();

    int jseg = 0, joff = 0;

    for (int j = 0; j < KD; ++j) {
        const int cur = j & 1;
        const int nxt = cur ^ 1;

        const float pinv = 1.0f / prow[cur][jseg * 20 + joff];
        const float4 f4 = *(const float4*)&pcol[cur][r0];

        const float4 q0 = *(const float4*)&prow[cur][seg + 0];
        const float4 q1 = *(const float4*)&prow[cur][seg + 4];
        const float4 q2 = *(const float4*)&prow[cur][seg + 8];
        const float4 q3 = *(const float4*)&prow[cur][seg + 12];
        const float p0 = q0.x, p1 = q0.y, p2 = q0.z, p3 = q0.w;
        const float p4 = q1.x, p5 = q1.y, p6 = q1.z, p7 = q1.w;
        const float p8 = q2.x, p9 = q2.y, p10 = q2.z, p11 = q2.w;
        const float p12 = q3.x, p13 = q3.y, p14 = q3.z;

        const float fw = f4.x * pinv, fx = f4.y * pinv;
        const float fy = f4.z * pinv, fz = f4.w * pinv;

        #define UPD(I) w##I = fmaf(-fw, p##I, w##I); x##I = fmaf(-fx, p##I, x##I); \
                       y##I = fmaf(-fy, p##I, y##I); z##I = fmaf(-fz, p##I, z##I);
        FOR15(UPD)
        #undef UPD

        if (rg == (j >> 2)) {
            #define FW(I) w##I = p##I * pinv;
            #define FX(I) x##I = p##I * pinv;
            #define FY(I) y##I = p##I * pinv;
            #define FZ(I) z##I = p##I * pinv;
            switch (j & 3) {
                case 0: FOR15(FW) break;
                case 1: FOR15(FX) break;
                case 2: FOR15(FY) break;
                default: FOR15(FZ) break;
            }
            #undef FW
            #undef FX
            #undef FY
            #undef FZ
        }

        const int j2 = j + 1;

        if (j2 < KD && rg == (j2 >> 2)) {
            #define PW(I) prow[nxt][seg + (I)] = w##I;
            #define PX(I) prow[nxt][seg + (I)] = x##I;
            #define PY(I) prow[nxt][seg + (I)] = y##I;
            #define PZ(I) prow[nxt][seg + (I)] = z##I;
            switch (j2 & 3) {
                case 0: FOR15(PW) break;
                case 1: FOR15(PX) break;
                case 2: FOR15(PY) break;
                default: FOR15(PZ) break;
            }
            #undef PW
            #undef PX
            #undef PY
            #undef PZ
        }

        joff++; if (joff == 15) { joff = 0; jseg++; }
        if (j2 < KD && cg == jseg) {
            #define PC(I) case I: *(float4*)&pcol[nxt][r0] = float4{w##I, x##I, y##I, z##I}; break;
            switch (joff) {
                FOR15(PC)
                default: break;
            }
            #undef PC
        }
        __syncthreads();
    }

    if (cg >= 8) {
        float* op = out + (size_t)pair * NB * KD * KD + (size_t)b * KD * KD;
        #define OUTW(I) { const int l = cbase + (I) - KD; \
                          *(float4*)&op[l * KD + r0] = float4{w##I, x##I, y##I, z##I}; }
        FOR15(OUTW)
        #undef OUTW
    }
}

// ---------------------------------------------------------------------------
extern "C" void kernel_launch(void* const* d_in, const int* in_sizes, int n_in,
                              void* d_out, int out_size, void* d_ws, size_t ws_size,
                              hipStream_t stream)
{
    const float* feat_x  = (const float*)d_in[0];
    const float* feat_y  = (const float*)d_in[1];
    const float* evecs_x = (const float*)d_in[2];
    const float* evecs_y = (const float*)d_in[3];
    float* out = (float*)d_out;

    // ws layout (floats): partials NCH*2*NB slabs of 352*120 = 6,758,400 (27MB)
    // | ftf/gtg/ftg 230,400 ea AFTER partials (gram_fused reads partials while
    // writing these — must NOT alias). Total ~29.8 MB.
    float* ws       = (float*)d_ws;
    float* partials = ws;
    float* ftf      = partials + (size_t)NCH * 2 * NB * SLABSZ;
    float* gtg      = ftf + (size_t)NB * KD * KD;
    float* ftg      = gtg + (size_t)NB * KD * KD;

    proj_mfma <<<dim3(15, 2, NB), 256, 0, stream>>>(feat_x, feat_y, evecs_x, evecs_y, partials);
    gram_fused<<<dim3(4, 3, NB), 256, 0, stream>>>(partials, ftf, gtg, ftg);
    solve_kernel<<<dim3(2, NB), 480, 0, stream>>>(ftf, gtg, ftg, out);
}